// Round 16
// baseline (252.630 us; speedup 1.0000x reference)
//
#include <hip/hip_runtime.h>

// ---------------- problem constants ----------------
#define NCONS 10000
#define NCOLSN 10000
#define NNODES 20000         // NCONS + NCOLSN
#define NEDGE 200000
#define NETOT 220000         // NEDGE + NNODES self loops
#define NEG_SLOPE 0.2f
#define NSCANB 79            // ceil(NNODES/256)

typedef unsigned short u16;
typedef __attribute__((ext_vector_type(8))) short bf16x8;
typedef __attribute__((ext_vector_type(4))) float f32x4;

__device__ __forceinline__ float bf2f(u16 u) {
  return __uint_as_float(((unsigned int)u) << 16);
}
__device__ __forceinline__ u16 f2bf(float f) {
  unsigned int x = __float_as_uint(f);
  return (u16)((x + 0x7fffu + ((x >> 16) & 1u)) >> 16);
}
__device__ __forceinline__ float lrelu(float v) {
  return v >= 0.f ? v : NEG_SLOPE * v;
}
// async global->LDS, 16 B per lane; LDS dest must be wave-uniform base + lane*16
__device__ __forceinline__ void gl2lds16(const u16* g, u16* l) {
  __builtin_amdgcn_global_load_lds(
      (const __attribute__((address_space(1))) unsigned int*)g,
      (__attribute__((address_space(3))) unsigned int*)l, 16, 0, 0);
}
__device__ __forceinline__ float readlane_f(float v, int j) {
  return __uint_as_float(__builtin_amdgcn_readlane(__float_as_uint(v), j));
}

#define W1N (1024 * 128)
#define W2N (128 * 1024)
#define OWN (128 * 128)
#define EMB0N (NNODES * 128)
#define WSDN (16 * 128)      // 16 fused attention vectors (8 ws + 8 wd), 128-dim

// ---------------- fused: layer-0 embed + weight cvt + wsd precompute + edge counting --------
__global__ void prep(const float* __restrict__ cons, const float* __restrict__ cols,
                     const float* __restrict__ nW, const float* __restrict__ nb,
                     const float* __restrict__ cW, const float* __restrict__ cb,
                     const float* __restrict__ W1, const float* __restrict__ W2,
                     const float* __restrict__ oW, const float* __restrict__ att_s1,
                     const float* __restrict__ att_d1, u16* __restrict__ emb,
                     u16* __restrict__ Wbf, u16* __restrict__ wsd,
                     const int* __restrict__ edges, int* __restrict__ counts) {
  int idx = blockIdx.x * 256 + threadIdx.x;
  if (idx < NETOT) {
    int dst = (idx < NEDGE) ? edges[NEDGE + idx] : (idx - NEDGE);
    atomicAdd(&counts[dst], 1);
  }
  if (idx < EMB0N) {
    int row = idx >> 7, o = idx & 127;
    float acc;
    if (row < NCONS) {
      acc = nb[o];
      #pragma unroll
      for (int k = 0; k < 4; ++k)
        acc += cons[row * 4 + k] * (nW[o * 8 + k] + nW[o * 8 + 4 + k]);
    } else {
      int r = row - NCONS;
      acc = cb[o];
      #pragma unroll
      for (int k = 0; k < 8; ++k)
        acc += cols[r * 8 + k] * (cW[o * 16 + k] + cW[o * 16 + 8 + k]);
    }
    emb[idx] = f2bf(fmaxf(acc, 0.f));
    return;
  }
  int i = idx - EMB0N;
  if (i < W1N + W2N + OWN) {
    float v;
    if (i < W1N) v = W1[i];
    else if (i < W1N + W2N) v = W2[i - W1N];
    else v = oW[i - W1N - W2N];
    Wbf[i] = f2bf(v);
    return;
  }
  int i2 = i - (W1N + W2N + OWN);
  if (i2 < WSDN) {
    int vec = i2 >> 7, k = i2 & 127;
    int h = vec & 7;
    const float* att = (vec < 8) ? att_s1 : att_d1;
    float a = 0.f;
    #pragma unroll 8
    for (int c = 0; c < 128; ++c)
      a += att[h * 128 + c] * W1[(size_t)(h * 128 + c) * 128 + k];
    wsd[i2] = f2bf(a);
  }
}

// ---------------- CSR build ----------------
__global__ void scan_a(const int* __restrict__ counts, int* __restrict__ lscan,
                       int* __restrict__ bsum) {
  __shared__ int sh[256];
  int t = threadIdx.x;
  int i = blockIdx.x * 256 + t;
  int v = (i < NNODES) ? counts[i] : 0;
  sh[t] = v;
  __syncthreads();
  for (int d = 1; d < 256; d <<= 1) {
    int add = (t >= d) ? sh[t - d] : 0;
    __syncthreads();
    sh[t] += add;
    __syncthreads();
  }
  lscan[i] = sh[t];
  if (t == 255) bsum[blockIdx.x] = sh[255];
}
__global__ void scan_c2(const int* __restrict__ lscan, const int* __restrict__ counts,
                        const int* __restrict__ bsum, int* __restrict__ offsets,
                        int* __restrict__ cursor) {
  __shared__ int sh[128];
  int t = threadIdx.x;
  if (t < 128) sh[t] = (t < NSCANB) ? bsum[t] : 0;
  __syncthreads();
  for (int d = 1; d < 128; d <<= 1) {
    int add = (t >= d && t < 128) ? sh[t - d] : 0;
    __syncthreads();
    if (t < 128) sh[t] += add;
    __syncthreads();
  }
  int bbase = (blockIdx.x > 0) ? sh[blockIdx.x - 1] : 0;
  int i = blockIdx.x * 256 + t;
  if (i == 0) offsets[0] = 0;
  if (i < NNODES) {
    int incl = lscan[i] + bbase;
    offsets[i + 1] = incl;
    cursor[i] = incl - counts[i];
  }
}

__global__ void fill_edges(const int* __restrict__ edges, int* __restrict__ cursor,
                           int* __restrict__ csr_src) {
  int i = blockIdx.x * 256 + threadIdx.x;
  if (i >= NETOT) return;
  int src, dst;
  if (i < NEDGE) { src = edges[i]; dst = edges[NEDGE + i]; }
  else { src = dst = i - NEDGE; }
  int pos = atomicAdd(&cursor[dst], 1);
  csr_src[pos] = src;
}

// ---------------- dots1: a_src/a_dst [N][8] = emb0 @ wsd^T via MFMA 16x16x32 ----------------
__global__ __launch_bounds__(256) void dots1_k(const u16* __restrict__ emb,
                                               const u16* __restrict__ wsd,
                                               float* __restrict__ as1,
                                               float* __restrict__ ad1) {
  int wv = threadIdx.x >> 6, lane = threadIdx.x & 63;
  int quad = lane >> 4, l16 = lane & 15;
  int m0 = blockIdx.x * 64 + wv * 16;
  int ra = m0 + l16; if (ra >= NNODES) ra = NNODES - 1;
  f32x4 acc = f32x4{0.f, 0.f, 0.f, 0.f};
  #pragma unroll
  for (int k0 = 0; k0 < 128; k0 += 32) {
    bf16x8 a = *(const bf16x8*)(emb + (size_t)ra * 128 + k0 + quad * 8);
    bf16x8 b = *(const bf16x8*)(wsd + (size_t)l16 * 128 + k0 + quad * 8);
    acc = __builtin_amdgcn_mfma_f32_16x16x32_bf16(a, b, acc, 0, 0, 0);
  }
  #pragma unroll
  for (int r = 0; r < 4; ++r) {
    int node = m0 + quad * 4 + r;
    if (node < NNODES) {
      if (l16 < 8) as1[node * 8 + l16] = acc[r];
      else         ad1[node * 8 + (l16 - 8)] = acc[r];
    }
  }
}

// ---------------- fused layer-1-transform + layer-2-transform GEMM ----------------
// 625 blocks x 32 rows. Phase 1: E = relu(agg@W1^T + b1) [32x1024] -> LDS (bf16, padded
// row stride 1028 u16 so phase-2 ds_read_b128 is conflict-free). Phase 2: xp2 = E @ W2^T,
// A-frags straight from LDS (no staging), B staged per 32-k tile. DOTS epilogue -> as2/ad2.
__global__ __launch_bounds__(256) void gemm12(const u16* __restrict__ agg,
                                              const u16* __restrict__ W1bf,
                                              const float* __restrict__ b1,
                                              const u16* __restrict__ W2bf,
                                              const float* __restrict__ att_s,
                                              const float* __restrict__ att_d,
                                              float* __restrict__ as2,
                                              float* __restrict__ ad2,
                                              u16* __restrict__ xp2) {
  __shared__ u16 E[32 * 1028];
  __shared__ u16 sA[32 * 32];
  __shared__ u16 sB[128 * 32];
  int tid = threadIdx.x;
  int wv = tid >> 6, lane = tid & 63, quad = lane >> 4, l16 = lane & 15;
  int m0 = blockIdx.x * 32;            // 625*32 == 20000 exactly, no clamp needed
  int rm = (wv >> 1) * 16, cn = (wv & 1) * 64;

  // ---- phase 1 ----
  for (int h = 0; h < 8; ++h) {
    f32x4 acc[4];
    #pragma unroll
    for (int ni = 0; ni < 4; ++ni) acc[ni] = f32x4{0.f, 0.f, 0.f, 0.f};
    for (int k0 = 0; k0 < 128; k0 += 32) {
      if (tid < 128) {                 // waves 0,1: stage A (32 rows x 64 B)
        int off = tid * 16;
        int row = off >> 6, kk = (off & 63) >> 1;
        gl2lds16(agg + (size_t)(m0 + row) * 1024 + h * 128 + k0 + kk, &sA[off >> 1]);
      }
      for (int off = tid * 16; off < 128 * 64; off += 4096) {   // stage B (W1 slice)
        int row = off >> 6, kk = (off & 63) >> 1;
        gl2lds16(W1bf + (size_t)(h * 128 + row) * 128 + k0 + kk, &sB[off >> 1]);
      }
      __syncthreads();
      bf16x8 af = *(const bf16x8*)&sA[(rm + l16) * 32 + quad * 8];
      #pragma unroll
      for (int ni = 0; ni < 4; ++ni) {
        bf16x8 bfv = *(const bf16x8*)&sB[(cn + ni * 16 + l16) * 32 + quad * 8];
        acc[ni] = __builtin_amdgcn_mfma_f32_16x16x32_bf16(af, bfv, acc[ni], 0, 0, 0);
      }
      __syncthreads();
    }
    #pragma unroll
    for (int ni = 0; ni < 4; ++ni) {
      int col = cn + ni * 16 + l16;
      float bv = b1[h * 128 + col];
      #pragma unroll
      for (int r = 0; r < 4; ++r) {
        int row = rm + quad * 4 + r;
        E[row * 1028 + h * 128 + col] = f2bf(fmaxf(acc[ni][r] + bv, 0.f));
      }
    }
    __syncthreads();
  }

  // ---- phase 2 ----
  f32x4 acc2[4];
  #pragma unroll
  for (int ni = 0; ni < 4; ++ni) acc2[ni] = f32x4{0.f, 0.f, 0.f, 0.f};
  for (int k0 = 0; k0 < 1024; k0 += 32) {
    for (int off = tid * 16; off < 128 * 64; off += 4096) {     // stage W2 tile
      int row = off >> 6, kk = (off & 63) >> 1;
      gl2lds16(W2bf + (size_t)row * 1024 + k0 + kk, &sB[off >> 1]);
    }
    __syncthreads();
    bf16x8 af = *(const bf16x8*)&E[(rm + l16) * 1028 + k0 + quad * 8];
    #pragma unroll
    for (int ni = 0; ni < 4; ++ni) {
      bf16x8 bfv = *(const bf16x8*)&sB[(cn + ni * 16 + l16) * 32 + quad * 8];
      acc2[ni] = __builtin_amdgcn_mfma_f32_16x16x32_bf16(af, bfv, acc2[ni], 0, 0, 0);
    }
    __syncthreads();
  }

  // DOTS epilogue (H=1) + xp2 write
  float av_s[4], av_d[4];
  #pragma unroll
  for (int ni = 0; ni < 4; ++ni) {
    int col = cn + ni * 16 + l16;
    av_s[ni] = att_s[col];
    av_d[ni] = att_d[col];
  }
  #pragma unroll
  for (int r = 0; r < 4; ++r) {
    float sp = 0.f, dp = 0.f;
    #pragma unroll
    for (int ni = 0; ni < 4; ++ni) {
      sp += acc2[ni][r] * av_s[ni];
      dp += acc2[ni][r] * av_d[ni];
    }
    #pragma unroll
    for (int w = 1; w < 16; w <<= 1) {
      sp += __shfl_xor(sp, w, 64);
      dp += __shfl_xor(dp, w, 64);
    }
    int orow = m0 + rm + quad * 4 + r;
    if (l16 == 0) {
      atomicAdd(&as2[orow], sp);
      atomicAdd(&ad2[orow], dp);
    }
  }
  #pragma unroll
  for (int ni = 0; ni < 4; ++ni) {
    int col = cn + ni * 16 + l16;
    #pragma unroll
    for (int r = 0; r < 4; ++r) {
      int orow = m0 + rm + quad * 4 + r;
      xp2[(size_t)orow * 128 + col] = f2bf(acc2[ni][r]);
    }
  }
}

// ---------------- LDS-staged GEMM (gemm3 only): C[M,N] = A[M,K] @ B[N,K]^T ----------------
template <int BM>
__global__ __launch_bounds__(256) void gemm_bt(const u16* __restrict__ A, const u16* __restrict__ B,
                                               const float* __restrict__ bias, float* __restrict__ C,
                                               int M, int N, int K) {
  constexpr int MI = BM / 32;
  __shared__ u16 sA[BM * 32];
  __shared__ u16 sB[128 * 32];
  int tid = threadIdx.x;
  int wv = tid >> 6;
  int lane = tid & 63;
  int quad = lane >> 4;
  int l16 = lane & 15;
  int m0 = blockIdx.x * BM;
  int rm = (wv >> 1) * (16 * MI);
  int cn = (wv & 1) * 64;

  f32x4 acc[MI][4];
  #pragma unroll
  for (int mi = 0; mi < MI; ++mi)
    #pragma unroll
    for (int ni = 0; ni < 4; ++ni) acc[mi][ni] = f32x4{0.f, 0.f, 0.f, 0.f};

  for (int k0 = 0; k0 < K; k0 += 32) {
    for (int off = tid * 16; off < BM * 64; off += 4096) {
      int row = off >> 6;
      int kk = (off & 63) >> 1;
      int rg = m0 + row; if (rg >= M) rg = M - 1;
      gl2lds16(A + (size_t)rg * K + k0 + kk, &sA[off >> 1]);
    }
    for (int off = tid * 16; off < 128 * 64; off += 4096) {
      int row = off >> 6;
      int kk = (off & 63) >> 1;
      gl2lds16(B + (size_t)row * K + k0 + kk, &sB[off >> 1]);
    }
    __syncthreads();
    bf16x8 af[MI], bfv[4];
    #pragma unroll
    for (int mi = 0; mi < MI; ++mi)
      af[mi] = *(const bf16x8*)&sA[(rm + mi * 16 + l16) * 32 + quad * 8];
    #pragma unroll
    for (int ni = 0; ni < 4; ++ni)
      bfv[ni] = *(const bf16x8*)&sB[(cn + ni * 16 + l16) * 32 + quad * 8];
    #pragma unroll
    for (int mi = 0; mi < MI; ++mi)
      #pragma unroll
      for (int ni = 0; ni < 4; ++ni)
        acc[mi][ni] = __builtin_amdgcn_mfma_f32_16x16x32_bf16(af[mi], bfv[ni], acc[mi][ni], 0, 0, 0);
    __syncthreads();
  }

  #pragma unroll
  for (int ni = 0; ni < 4; ++ni) {
    int col = cn + ni * 16 + l16;
    float bv = bias[col];
    #pragma unroll
    for (int mi = 0; mi < MI; ++mi) {
      #pragma unroll
      for (int r = 0; r < 4; ++r) {
        int orow = m0 + rm + mi * 16 + quad * 4 + r;
        if (orow < M) C[(size_t)orow * N + col] = acc[mi][ni][r] + bv;
      }
    }
  }
}

// ---------------- fagg1: fused softmax + multi-head aggregate, agg = A_alpha @ emb0 --------
__global__ __launch_bounds__(256) void fagg1(const int* __restrict__ offs,
                                             const int* __restrict__ csr_src,
                                             const float* __restrict__ as1,
                                             const float* __restrict__ ad1,
                                             const u16* __restrict__ emb,
                                             u16* __restrict__ agg) {
  __shared__ float alds[4 * 512];
  int wvi = threadIdx.x >> 6;
  int dst = blockIdx.x * 4 + wvi;
  if (dst >= NNODES) return;
  int l = threadIdx.x & 63;
  int h = l & 7, i = l >> 3;
  float* wlds = &alds[wvi * 512];
  int off = offs[dst];
  int deg = offs[dst + 1] - off;
  const int* srcs = csr_src + off;
  float adv = ad1[dst * 8 + h];
  const u16* base = emb + l * 2;
  float acc[8][2];
  #pragma unroll
  for (int hh = 0; hh < 8; ++hh) { acc[hh][0] = 0.f; acc[hh][1] = 0.f; }

  if (deg <= 64) {
    int sl = srcs[l < deg ? l : deg - 1];
    float g[8];
    #pragma unroll
    for (int t = 0; t < 8; ++t) {
      int jj = t * 8 + i;
      int s = __builtin_amdgcn_readlane(sl, jj < deg ? jj : 0);
      g[t] = as1[s * 8 + h];
    }
    float m = -1e30f, ssum = 0.f, ev[8];
    #pragma unroll
    for (int t = 0; t < 8; ++t) {
      int jj = t * 8 + i;
      float e = (jj < deg) ? lrelu(g[t] + adv) : -1e30f;
      ev[t] = e;
      float nm = fmaxf(m, e);
      ssum = ssum * __expf(m - nm) + ((jj < deg) ? __expf(e - nm) : 0.f);
      m = nm;
    }
    #pragma unroll
    for (int w = 8; w < 64; w <<= 1) {
      float om = __shfl_xor(m, w, 64);
      float os = __shfl_xor(ssum, w, 64);
      float nm = fmaxf(m, om);
      ssum = ssum * __expf(m - nm) + os * __expf(om - nm);
      m = nm;
    }
    float inv = 1.f / (ssum + 1e-16f);
    #pragma unroll
    for (int t = 0; t < 8; ++t)
      wlds[t * 64 + l] = __expf(ev[t] - m) * inv;
    for (int j0 = 0; j0 < deg; j0 += 8) {
      ushort2 uu[8];
      #pragma unroll
      for (int t2 = 0; t2 < 8; ++t2) {
        int slot = j0 + t2;
        int s = __builtin_amdgcn_readlane(sl, slot < deg ? slot : 0);
        uu[t2] = *(const ushort2*)(base + (size_t)s * 128);
      }
      #pragma unroll
      for (int t2 = 0; t2 < 8; ++t2) {
        int slot = j0 + t2;
        float x0 = bf2f(uu[t2].x), x1 = bf2f(uu[t2].y);
        #pragma unroll
        for (int hh = 0; hh < 8; ++hh) {
          float w = wlds[slot * 8 + hh];
          acc[hh][0] += w * x0;
          acc[hh][1] += w * x1;
        }
      }
    }
  } else {
    float m = -1e30f, ssum = 0.f;
    for (int j = i; j < deg; j += 8) {
      int s = srcs[j];
      float e = lrelu(as1[s * 8 + h] + adv);
      float nm = fmaxf(m, e);
      ssum = ssum * __expf(m - nm) + __expf(e - nm);
      m = nm;
    }
    #pragma unroll
    for (int w = 8; w < 64; w <<= 1) {
      float om = __shfl_xor(m, w, 64);
      float os = __shfl_xor(ssum, w, 64);
      float nm = fmaxf(m, om);
      ssum = ssum * __expf(m - nm) + os * __expf(om - nm);
      m = nm;
    }
    float inv = 1.f / (ssum + 1e-16f);
    for (int b0 = 0; b0 < deg; b0 += 64) {
      int cnt = deg - b0; if (cnt > 64) cnt = 64;
      #pragma unroll
      for (int t = 0; t < 8; ++t) {
        int sl2 = t * 8 + i;
        float a = 0.f;
        if (sl2 < cnt) {
          int s = srcs[b0 + sl2];
          a = __expf(lrelu(as1[s * 8 + h] + adv) - m) * inv;
        }
        wlds[t * 64 + l] = a;
      }
      int sv = srcs[b0 + (l < cnt ? l : cnt - 1)];
      for (int j0 = 0; j0 < cnt; j0 += 8) {
        ushort2 uu[8];
        #pragma unroll
        for (int t2 = 0; t2 < 8; ++t2) {
          int slot = j0 + t2;
          int s = __builtin_amdgcn_readlane(sv, slot < cnt ? slot : 0);
          uu[t2] = *(const ushort2*)(base + (size_t)s * 128);
        }
        #pragma unroll
        for (int t2 = 0; t2 < 8; ++t2) {
          int slot = j0 + t2;
          float x0 = bf2f(uu[t2].x), x1 = bf2f(uu[t2].y);
          #pragma unroll
          for (int hh = 0; hh < 8; ++hh) {
            float w = wlds[slot * 8 + hh];
            acc[hh][0] += w * x0;
            acc[hh][1] += w * x1;
          }
        }
      }
    }
  }
  #pragma unroll
  for (int hh = 0; hh < 8; ++hh) {
    ushort2 o;
    o.x = f2bf(acc[hh][0]);
    o.y = f2bf(acc[hh][1]);
    *(ushort2*)(agg + (size_t)dst * 1024 + hh * 128 + l * 2) = o;
  }
}

// ---------------- fused softmax + SpMM layer2 (H=1), dst in [NCONS, NNODES) ----------------
__global__ __launch_bounds__(256) void fsp2(const int* __restrict__ offs,
                                            const int* __restrict__ csr_src,
                                            const float* __restrict__ a_src,
                                            const float* __restrict__ a_dst,
                                            const u16* __restrict__ xp2,
                                            const float* __restrict__ bias,
                                            u16* __restrict__ out) {
  int wvi = threadIdx.x >> 6;
  int dst = NCONS + blockIdx.x * 4 + wvi;
  if (dst >= NNODES) return;
  int l = threadIdx.x & 63;
  int off = offs[dst];
  int deg = offs[dst + 1] - off;
  const int* srcs = csr_src + off;
  float ad = a_dst[dst];
  const u16* base = xp2 + l * 2;
  float m = -1e30f, ssum = 0.f, a0 = 0.f, a1 = 0.f;
  for (int b0 = 0; b0 < deg; b0 += 64) {
    int cnt = deg - b0; if (cnt > 64) cnt = 64;
    int sv = srcs[b0 + (l < cnt ? l : cnt - 1)];
    float e = (l < cnt) ? lrelu(a_src[sv] + ad) : -1e30f;
    float mc = e;
    #pragma unroll
    for (int w = 1; w < 64; w <<= 1) mc = fmaxf(mc, __shfl_xor(mc, w, 64));
    float pex = __expf(e - mc);
    float sc = pex;
    #pragma unroll
    for (int w = 1; w < 64; w <<= 1) sc += __shfl_xor(sc, w, 64);
    float c0 = 0.f, c1 = 0.f;
    int j = 0;
    for (; j + 8 <= cnt; j += 8) {
      ushort2 uu[8];
      float ww[8];
      #pragma unroll
      for (int t = 0; t < 8; ++t) {
        int s = __builtin_amdgcn_readlane(sv, j + t);
        ww[t] = readlane_f(pex, j + t);
        uu[t] = *(const ushort2*)(base + (size_t)s * 128);
      }
      #pragma unroll
      for (int t = 0; t < 8; ++t) {
        c0 += ww[t] * bf2f(uu[t].x);
        c1 += ww[t] * bf2f(uu[t].y);
      }
    }
    for (; j < cnt; ++j) {
      int s = __builtin_amdgcn_readlane(sv, j);
      float w = readlane_f(pex, j);
      ushort2 u = *(const ushort2*)(base + (size_t)s * 128);
      c0 += w * bf2f(u.x);
      c1 += w * bf2f(u.y);
    }
    float nm = fmaxf(m, mc);
    float fo = __expf(m - nm), fn = __expf(mc - nm);
    a0 = a0 * fo + c0 * fn;
    a1 = a1 * fo + c1 * fn;
    ssum = ssum * fo + sc * fn;
    m = nm;
  }
  float inv = 1.f / (ssum + 1e-16f);
  int cg = l * 2;
  ushort2 o;
  o.x = f2bf(fmaxf(a0 * inv + bias[cg], 0.f));
  o.y = f2bf(fmaxf(a1 * inv + bias[cg + 1], 0.f));
  *(ushort2*)(out + (size_t)dst * 128 + cg) = o;
}

// ---------------- launch ----------------
extern "C" void kernel_launch(void* const* d_in, const int* in_sizes, int n_in,
                              void* d_out, int out_size, void* d_ws, size_t ws_size,
                              hipStream_t stream) {
  const float* cons    = (const float*)d_in[0];
  const float* cols    = (const float*)d_in[1];
  const float* node_W  = (const float*)d_in[2];
  const float* node_b  = (const float*)d_in[3];
  const float* col_W   = (const float*)d_in[4];
  const float* col_b   = (const float*)d_in[5];
  const float* W1      = (const float*)d_in[6];
  const float* att_s1  = (const float*)d_in[7];
  const float* att_d1  = (const float*)d_in[8];
  const float* b1      = (const float*)d_in[9];
  const float* W2      = (const float*)d_in[10];
  const float* att_s2  = (const float*)d_in[11];
  const float* att_d2  = (const float*)d_in[12];
  const float* b2      = (const float*)d_in[13];
  const float* out_W   = (const float*)d_in[14];
  const float* out_b   = (const float*)d_in[15];
  const int* edges     = (const int*)d_in[16];

  char* p = (char*)d_ws;
  auto alloc = [&](size_t bytes) {
    char* r = p;
    p += (bytes + 255) & ~(size_t)255;
    return r;
  };
  u16* emb0    = (u16*)alloc((size_t)NNODES * 128 * 2);        // bf16
  u16* agg     = (u16*)alloc((size_t)NNODES * 1024 * 2);       // bf16, node-major [N][8*128]
  u16* xp2     = (u16*)alloc((size_t)NNODES * 128 * 2);        // bf16
  u16* emb3    = (u16*)alloc((size_t)NNODES * 128 * 2);        // bf16
  u16* Wbf     = (u16*)alloc((size_t)(W1N + W2N + OWN) * 2);   // W1|W2|out_W contiguous
  u16* wsd     = (u16*)alloc((size_t)WSDN * 2);                // fused att vectors bf16
  // ---- contiguous zero region: as2, ad2, counts ----
  float* as2   = (float*)alloc((size_t)NNODES * 4);            // pads to 80128 B
  float* ad2   = (float*)alloc((size_t)NNODES * 4);            // pads to 80128 B
  int* counts  = (int*)alloc((size_t)NNODES * 4);              // pads to 80128 B
  size_t zspan = (char*)(counts + NNODES) - (char*)as2;
  // ---- end zero region ----
  float* as1   = (float*)alloc((size_t)NNODES * 8 * 4);
  float* ad1   = (float*)alloc((size_t)NNODES * 8 * 4);
  int* offs    = (int*)alloc((size_t)(NNODES + 1) * 4);
  int* cursor  = (int*)alloc((size_t)NNODES * 4);
  int* csrsrc  = (int*)alloc((size_t)NETOT * 4);
  int* lscan   = (int*)alloc((size_t)NSCANB * 256 * 4);
  int* bsum    = (int*)alloc((size_t)NSCANB * 4);

  u16* W1bf = Wbf;
  u16* W2bf = Wbf + W1N;
  u16* oWbf = Wbf + W1N + W2N;

  hipMemsetAsync(as2, 0, zspan, stream);

  // layer-0 embed + weight cvt + wsd + edge counting (fused)
  prep<<<(EMB0N + W1N + W2N + OWN + WSDN + 255) / 256, 256, 0, stream>>>(
      cons, cols, node_W, node_b, col_W, col_b, W1, W2, out_W, att_s1, att_d1,
      emb0, Wbf, wsd, edges, counts);

  // CSR build
  scan_a<<<NSCANB, 256, 0, stream>>>(counts, lscan, bsum);
  scan_c2<<<NSCANB, 256, 0, stream>>>(lscan, counts, bsum, offs, cursor);
  fill_edges<<<(NETOT + 255) / 256, 256, 0, stream>>>(edges, cursor, csrsrc);

  // GAT layer 1 (aggregate-then-transform): dots -> fused softmax+aggregate
  dots1_k<<<(NNODES + 63) / 64, 256, 0, stream>>>(emb0, wsd, as1, ad1);
  fagg1<<<(NNODES + 3) / 4, 256, 0, stream>>>(offs, csrsrc, as1, ad1, emb0, agg);

  // fused transform: emb2 = relu(agg@W1^T+b1) (LDS-only) -> xp2 = emb2@W2^T (+dots2)
  gemm12<<<NNODES / 32, 256, 0, stream>>>(agg, W1bf, b1, W2bf, att_s2, att_d2,
                                          as2, ad2, xp2);

  // GAT layer 2 aggregation: fused softmax+SpMM (dst >= NCONS only)
  fsp2<<<(NCOLSN + 3) / 4, 256, 0, stream>>>(offs, csrsrc, as2, ad2, xp2, b2, emb3);

  // output projection: rows 10000..19999, f32 out with bias
  gemm_bt<32><<<(NCOLSN + 31) / 32, 256, 0, stream>>>(
      emb3 + (size_t)NCONS * 128, oWbf, out_b, (float*)d_out, NCOLSN, 128, 128);
}

// Round 17
// 232.271 us; speedup vs baseline: 1.0877x; 1.0877x over previous
//
#include <hip/hip_runtime.h>

// ---------------- problem constants ----------------
#define NCONS 10000
#define NCOLSN 10000
#define NNODES 20000         // NCONS + NCOLSN
#define NEDGE 200000
#define NETOT 220000         // NEDGE + NNODES self loops
#define NEG_SLOPE 0.2f
#define NSCANB 79            // ceil(NNODES/256)

typedef unsigned short u16;
typedef __attribute__((ext_vector_type(8))) short bf16x8;
typedef __attribute__((ext_vector_type(4))) float f32x4;

__device__ __forceinline__ float bf2f(u16 u) {
  return __uint_as_float(((unsigned int)u) << 16);
}
__device__ __forceinline__ u16 f2bf(float f) {
  unsigned int x = __float_as_uint(f);
  return (u16)((x + 0x7fffu + ((x >> 16) & 1u)) >> 16);
}
__device__ __forceinline__ float lrelu(float v) {
  return v >= 0.f ? v : NEG_SLOPE * v;
}
// async global->LDS, 16 B per lane; LDS dest must be wave-uniform base + lane*16
__device__ __forceinline__ void gl2lds16(const u16* g, u16* l) {
  __builtin_amdgcn_global_load_lds(
      (const __attribute__((address_space(1))) unsigned int*)g,
      (__attribute__((address_space(3))) unsigned int*)l, 16, 0, 0);
}
__device__ __forceinline__ float readlane_f(float v, int j) {
  return __uint_as_float(__builtin_amdgcn_readlane(__float_as_uint(v), j));
}

#define W1N (1024 * 128)
#define W2N (128 * 1024)
#define OWN (128 * 128)
#define EMB0N (NNODES * 128)
#define WSDN (16 * 128)      // 16 fused attention vectors (8 ws + 8 wd), 128-dim

// ---------------- fused: layer-0 embed + weight cvt + wsd precompute + edge counting --------
__global__ void prep(const float* __restrict__ cons, const float* __restrict__ cols,
                     const float* __restrict__ nW, const float* __restrict__ nb,
                     const float* __restrict__ cW, const float* __restrict__ cb,
                     const float* __restrict__ W1, const float* __restrict__ W2,
                     const float* __restrict__ oW, const float* __restrict__ att_s1,
                     const float* __restrict__ att_d1, u16* __restrict__ emb,
                     u16* __restrict__ Wbf, u16* __restrict__ wsd,
                     const int* __restrict__ edges, int* __restrict__ counts) {
  int idx = blockIdx.x * 256 + threadIdx.x;
  if (idx < NETOT) {
    int dst = (idx < NEDGE) ? edges[NEDGE + idx] : (idx - NEDGE);
    atomicAdd(&counts[dst], 1);
  }
  if (idx < EMB0N) {
    int row = idx >> 7, o = idx & 127;
    float acc;
    if (row < NCONS) {
      acc = nb[o];
      #pragma unroll
      for (int k = 0; k < 4; ++k)
        acc += cons[row * 4 + k] * (nW[o * 8 + k] + nW[o * 8 + 4 + k]);
    } else {
      int r = row - NCONS;
      acc = cb[o];
      #pragma unroll
      for (int k = 0; k < 8; ++k)
        acc += cols[r * 8 + k] * (cW[o * 16 + k] + cW[o * 16 + 8 + k]);
    }
    emb[idx] = f2bf(fmaxf(acc, 0.f));
    return;
  }
  int i = idx - EMB0N;
  if (i < W1N + W2N + OWN) {
    float v;
    if (i < W1N) v = W1[i];
    else if (i < W1N + W2N) v = W2[i - W1N];
    else v = oW[i - W1N - W2N];
    Wbf[i] = f2bf(v);
    return;
  }
  int i2 = i - (W1N + W2N + OWN);
  if (i2 < WSDN) {
    int vec = i2 >> 7, k = i2 & 127;
    int h = vec & 7;
    const float* att = (vec < 8) ? att_s1 : att_d1;
    float a = 0.f;
    #pragma unroll 8
    for (int c = 0; c < 128; ++c)
      a += att[h * 128 + c] * W1[(size_t)(h * 128 + c) * 128 + k];
    wsd[i2] = f2bf(a);
  }
}

// ---------------- CSR build ----------------
__global__ void scan_a(const int* __restrict__ counts, int* __restrict__ lscan,
                       int* __restrict__ bsum) {
  __shared__ int sh[256];
  int t = threadIdx.x;
  int i = blockIdx.x * 256 + t;
  int v = (i < NNODES) ? counts[i] : 0;
  sh[t] = v;
  __syncthreads();
  for (int d = 1; d < 256; d <<= 1) {
    int add = (t >= d) ? sh[t - d] : 0;
    __syncthreads();
    sh[t] += add;
    __syncthreads();
  }
  lscan[i] = sh[t];
  if (t == 255) bsum[blockIdx.x] = sh[255];
}
__global__ void scan_c2(const int* __restrict__ lscan, const int* __restrict__ counts,
                        const int* __restrict__ bsum, int* __restrict__ offsets,
                        int* __restrict__ cursor) {
  __shared__ int sh[128];
  int t = threadIdx.x;
  if (t < 128) sh[t] = (t < NSCANB) ? bsum[t] : 0;
  __syncthreads();
  for (int d = 1; d < 128; d <<= 1) {
    int add = (t >= d && t < 128) ? sh[t - d] : 0;
    __syncthreads();
    if (t < 128) sh[t] += add;
    __syncthreads();
  }
  int bbase = (blockIdx.x > 0) ? sh[blockIdx.x - 1] : 0;
  int i = blockIdx.x * 256 + t;
  if (i == 0) offsets[0] = 0;
  if (i < NNODES) {
    int incl = lscan[i] + bbase;
    offsets[i + 1] = incl;
    cursor[i] = incl - counts[i];
  }
}

__global__ void fill_edges(const int* __restrict__ edges, int* __restrict__ cursor,
                           int* __restrict__ csr_src) {
  int i = blockIdx.x * 256 + threadIdx.x;
  if (i >= NETOT) return;
  int src, dst;
  if (i < NEDGE) { src = edges[i]; dst = edges[NEDGE + i]; }
  else { src = dst = i - NEDGE; }
  int pos = atomicAdd(&cursor[dst], 1);
  csr_src[pos] = src;
}

// ---------------- dots1: a_src/a_dst [N][8] = emb0 @ wsd^T via MFMA 16x16x32 ----------------
__global__ __launch_bounds__(256) void dots1_k(const u16* __restrict__ emb,
                                               const u16* __restrict__ wsd,
                                               float* __restrict__ as1,
                                               float* __restrict__ ad1) {
  int wv = threadIdx.x >> 6, lane = threadIdx.x & 63;
  int quad = lane >> 4, l16 = lane & 15;
  int m0 = blockIdx.x * 64 + wv * 16;
  int ra = m0 + l16; if (ra >= NNODES) ra = NNODES - 1;
  f32x4 acc = f32x4{0.f, 0.f, 0.f, 0.f};
  #pragma unroll
  for (int k0 = 0; k0 < 128; k0 += 32) {
    bf16x8 a = *(const bf16x8*)(emb + (size_t)ra * 128 + k0 + quad * 8);
    bf16x8 b = *(const bf16x8*)(wsd + (size_t)l16 * 128 + k0 + quad * 8);
    acc = __builtin_amdgcn_mfma_f32_16x16x32_bf16(a, b, acc, 0, 0, 0);
  }
  #pragma unroll
  for (int r = 0; r < 4; ++r) {
    int node = m0 + quad * 4 + r;
    if (node < NNODES) {
      if (l16 < 8) as1[node * 8 + l16] = acc[r];
      else         ad1[node * 8 + (l16 - 8)] = acc[r];
    }
  }
}

// ---------------- fused per-head-interleaved transform GEMM ----------------
// 625 blocks x 32 rows. For each head h: E_h = relu(agg_h@W1_h^T + b1_h) [32x128] -> LDS
// chunk (row stride 136 u16: bank spread (68*l16+4q)%32 uniform -> conflict-free b128),
// immediately accumulate xp2 += E_h @ W2[:, h*128:+128]^T. LDS ~18.9 KB total.
// DOTS epilogue -> as2/ad2 atomics, xp2 store.
__global__ __launch_bounds__(256) void gemm12(const u16* __restrict__ agg,
                                              const u16* __restrict__ W1bf,
                                              const float* __restrict__ b1,
                                              const u16* __restrict__ W2bf,
                                              const float* __restrict__ att_s,
                                              const float* __restrict__ att_d,
                                              float* __restrict__ as2,
                                              float* __restrict__ ad2,
                                              u16* __restrict__ xp2) {
  __shared__ u16 sE[32 * 136];
  __shared__ u16 sA[32 * 32];
  __shared__ u16 sB[128 * 32];
  int tid = threadIdx.x;
  int wv = tid >> 6, lane = tid & 63, quad = lane >> 4, l16 = lane & 15;
  int m0 = blockIdx.x * 32;            // 625*32 == 20000 exactly
  int rm = (wv >> 1) * 16, cn = (wv & 1) * 64;

  f32x4 acc2[4];
  #pragma unroll
  for (int ni = 0; ni < 4; ++ni) acc2[ni] = f32x4{0.f, 0.f, 0.f, 0.f};

  for (int h = 0; h < 8; ++h) {
    // phase A: E_h = relu(agg_h @ W1_h^T + b1_h), K=128
    f32x4 acc1[4];
    #pragma unroll
    for (int ni = 0; ni < 4; ++ni) acc1[ni] = f32x4{0.f, 0.f, 0.f, 0.f};
    #pragma unroll
    for (int k0 = 0; k0 < 128; k0 += 32) {
      if (tid < 128) {                 // waves 0,1: stage A (32 rows x 64 B)
        int off = tid * 16;
        int row = off >> 6, kk = (off & 63) >> 1;
        gl2lds16(agg + (size_t)(m0 + row) * 1024 + h * 128 + k0 + kk, &sA[off >> 1]);
      }
      for (int off = tid * 16; off < 128 * 64; off += 4096) {   // stage B (W1 head slice)
        int row = off >> 6, kk = (off & 63) >> 1;
        gl2lds16(W1bf + (size_t)(h * 128 + row) * 128 + k0 + kk, &sB[off >> 1]);
      }
      __syncthreads();
      bf16x8 af = *(const bf16x8*)&sA[(rm + l16) * 32 + quad * 8];
      #pragma unroll
      for (int ni = 0; ni < 4; ++ni) {
        bf16x8 bfv = *(const bf16x8*)&sB[(cn + ni * 16 + l16) * 32 + quad * 8];
        acc1[ni] = __builtin_amdgcn_mfma_f32_16x16x32_bf16(af, bfv, acc1[ni], 0, 0, 0);
      }
      __syncthreads();
    }
    #pragma unroll
    for (int ni = 0; ni < 4; ++ni) {
      int col = cn + ni * 16 + l16;
      float bv = b1[h * 128 + col];
      #pragma unroll
      for (int r = 0; r < 4; ++r) {
        int row = rm + quad * 4 + r;
        sE[row * 136 + col] = f2bf(fmaxf(acc1[ni][r] + bv, 0.f));
      }
    }
    __syncthreads();
    // phase B: xp2 += E_h @ W2[:, h*128:+128]^T
    #pragma unroll
    for (int k0 = 0; k0 < 128; k0 += 32) {
      for (int off = tid * 16; off < 128 * 64; off += 4096) {   // stage W2 k-slice
        int row = off >> 6, kk = (off & 63) >> 1;
        gl2lds16(W2bf + (size_t)row * 1024 + h * 128 + k0 + kk, &sB[off >> 1]);
      }
      __syncthreads();
      bf16x8 af = *(const bf16x8*)&sE[(rm + l16) * 136 + k0 + quad * 8];
      #pragma unroll
      for (int ni = 0; ni < 4; ++ni) {
        bf16x8 bfv = *(const bf16x8*)&sB[(cn + ni * 16 + l16) * 32 + quad * 8];
        acc2[ni] = __builtin_amdgcn_mfma_f32_16x16x32_bf16(af, bfv, acc2[ni], 0, 0, 0);
      }
      __syncthreads();
    }
  }

  // DOTS epilogue (H=1) + xp2 write
  float av_s[4], av_d[4];
  #pragma unroll
  for (int ni = 0; ni < 4; ++ni) {
    int col = cn + ni * 16 + l16;
    av_s[ni] = att_s[col];
    av_d[ni] = att_d[col];
  }
  #pragma unroll
  for (int r = 0; r < 4; ++r) {
    float sp = 0.f, dp = 0.f;
    #pragma unroll
    for (int ni = 0; ni < 4; ++ni) {
      sp += acc2[ni][r] * av_s[ni];
      dp += acc2[ni][r] * av_d[ni];
    }
    #pragma unroll
    for (int w = 1; w < 16; w <<= 1) {
      sp += __shfl_xor(sp, w, 64);
      dp += __shfl_xor(dp, w, 64);
    }
    int orow = m0 + rm + quad * 4 + r;
    if (l16 == 0) {
      atomicAdd(&as2[orow], sp);
      atomicAdd(&ad2[orow], dp);
    }
  }
  #pragma unroll
  for (int ni = 0; ni < 4; ++ni) {
    int col = cn + ni * 16 + l16;
    #pragma unroll
    for (int r = 0; r < 4; ++r) {
      int orow = m0 + rm + quad * 4 + r;
      xp2[(size_t)orow * 128 + col] = f2bf(acc2[ni][r]);
    }
  }
}

// ---------------- LDS-staged GEMM (gemm3 only): C[M,N] = A[M,K] @ B[N,K]^T ----------------
template <int BM>
__global__ __launch_bounds__(256) void gemm_bt(const u16* __restrict__ A, const u16* __restrict__ B,
                                               const float* __restrict__ bias, float* __restrict__ C,
                                               int M, int N, int K) {
  constexpr int MI = BM / 32;
  __shared__ u16 sA[BM * 32];
  __shared__ u16 sB[128 * 32];
  int tid = threadIdx.x;
  int wv = tid >> 6;
  int lane = tid & 63;
  int quad = lane >> 4;
  int l16 = lane & 15;
  int m0 = blockIdx.x * BM;
  int rm = (wv >> 1) * (16 * MI);
  int cn = (wv & 1) * 64;

  f32x4 acc[MI][4];
  #pragma unroll
  for (int mi = 0; mi < MI; ++mi)
    #pragma unroll
    for (int ni = 0; ni < 4; ++ni) acc[mi][ni] = f32x4{0.f, 0.f, 0.f, 0.f};

  for (int k0 = 0; k0 < K; k0 += 32) {
    for (int off = tid * 16; off < BM * 64; off += 4096) {
      int row = off >> 6;
      int kk = (off & 63) >> 1;
      int rg = m0 + row; if (rg >= M) rg = M - 1;
      gl2lds16(A + (size_t)rg * K + k0 + kk, &sA[off >> 1]);
    }
    for (int off = tid * 16; off < 128 * 64; off += 4096) {
      int row = off >> 6;
      int kk = (off & 63) >> 1;
      gl2lds16(B + (size_t)row * K + k0 + kk, &sB[off >> 1]);
    }
    __syncthreads();
    bf16x8 af[MI], bfv[4];
    #pragma unroll
    for (int mi = 0; mi < MI; ++mi)
      af[mi] = *(const bf16x8*)&sA[(rm + mi * 16 + l16) * 32 + quad * 8];
    #pragma unroll
    for (int ni = 0; ni < 4; ++ni)
      bfv[ni] = *(const bf16x8*)&sB[(cn + ni * 16 + l16) * 32 + quad * 8];
    #pragma unroll
    for (int mi = 0; mi < MI; ++mi)
      #pragma unroll
      for (int ni = 0; ni < 4; ++ni)
        acc[mi][ni] = __builtin_amdgcn_mfma_f32_16x16x32_bf16(af[mi], bfv[ni], acc[mi][ni], 0, 0, 0);
    __syncthreads();
  }

  #pragma unroll
  for (int ni = 0; ni < 4; ++ni) {
    int col = cn + ni * 16 + l16;
    float bv = bias[col];
    #pragma unroll
    for (int mi = 0; mi < MI; ++mi) {
      #pragma unroll
      for (int r = 0; r < 4; ++r) {
        int orow = m0 + rm + mi * 16 + quad * 4 + r;
        if (orow < M) C[(size_t)orow * N + col] = acc[mi][ni][r] + bv;
      }
    }
  }
}

// ---------------- fagg1: fused softmax + multi-head aggregate, agg = A_alpha @ emb0 --------
__global__ __launch_bounds__(256) void fagg1(const int* __restrict__ offs,
                                             const int* __restrict__ csr_src,
                                             const float* __restrict__ as1,
                                             const float* __restrict__ ad1,
                                             const u16* __restrict__ emb,
                                             u16* __restrict__ agg) {
  __shared__ float alds[4 * 512];
  int wvi = threadIdx.x >> 6;
  int dst = blockIdx.x * 4 + wvi;
  if (dst >= NNODES) return;
  int l = threadIdx.x & 63;
  int h = l & 7, i = l >> 3;
  float* wlds = &alds[wvi * 512];
  int off = offs[dst];
  int deg = offs[dst + 1] - off;
  const int* srcs = csr_src + off;
  float adv = ad1[dst * 8 + h];
  const u16* base = emb + l * 2;
  float acc[8][2];
  #pragma unroll
  for (int hh = 0; hh < 8; ++hh) { acc[hh][0] = 0.f; acc[hh][1] = 0.f; }

  if (deg <= 64) {
    int sl = srcs[l < deg ? l : deg - 1];
    float g[8];
    #pragma unroll
    for (int t = 0; t < 8; ++t) {
      int jj = t * 8 + i;
      int s = __builtin_amdgcn_readlane(sl, jj < deg ? jj : 0);
      g[t] = as1[s * 8 + h];
    }
    float m = -1e30f, ssum = 0.f, ev[8];
    #pragma unroll
    for (int t = 0; t < 8; ++t) {
      int jj = t * 8 + i;
      float e = (jj < deg) ? lrelu(g[t] + adv) : -1e30f;
      ev[t] = e;
      float nm = fmaxf(m, e);
      ssum = ssum * __expf(m - nm) + ((jj < deg) ? __expf(e - nm) : 0.f);
      m = nm;
    }
    #pragma unroll
    for (int w = 8; w < 64; w <<= 1) {
      float om = __shfl_xor(m, w, 64);
      float os = __shfl_xor(ssum, w, 64);
      float nm = fmaxf(m, om);
      ssum = ssum * __expf(m - nm) + os * __expf(om - nm);
      m = nm;
    }
    float inv = 1.f / (ssum + 1e-16f);
    #pragma unroll
    for (int t = 0; t < 8; ++t)
      wlds[t * 64 + l] = __expf(ev[t] - m) * inv;
    for (int j0 = 0; j0 < deg; j0 += 8) {
      ushort2 uu[8];
      #pragma unroll
      for (int t2 = 0; t2 < 8; ++t2) {
        int slot = j0 + t2;
        int s = __builtin_amdgcn_readlane(sl, slot < deg ? slot : 0);
        uu[t2] = *(const ushort2*)(base + (size_t)s * 128);
      }
      #pragma unroll
      for (int t2 = 0; t2 < 8; ++t2) {
        int slot = j0 + t2;
        float x0 = bf2f(uu[t2].x), x1 = bf2f(uu[t2].y);
        #pragma unroll
        for (int hh = 0; hh < 8; ++hh) {
          float w = wlds[slot * 8 + hh];
          acc[hh][0] += w * x0;
          acc[hh][1] += w * x1;
        }
      }
    }
  } else {
    float m = -1e30f, ssum = 0.f;
    for (int j = i; j < deg; j += 8) {
      int s = srcs[j];
      float e = lrelu(as1[s * 8 + h] + adv);
      float nm = fmaxf(m, e);
      ssum = ssum * __expf(m - nm) + __expf(e - nm);
      m = nm;
    }
    #pragma unroll
    for (int w = 8; w < 64; w <<= 1) {
      float om = __shfl_xor(m, w, 64);
      float os = __shfl_xor(ssum, w, 64);
      float nm = fmaxf(m, om);
      ssum = ssum * __expf(m - nm) + os * __expf(om - nm);
      m = nm;
    }
    float inv = 1.f / (ssum + 1e-16f);
    for (int b0 = 0; b0 < deg; b0 += 64) {
      int cnt = deg - b0; if (cnt > 64) cnt = 64;
      #pragma unroll
      for (int t = 0; t < 8; ++t) {
        int sl2 = t * 8 + i;
        float a = 0.f;
        if (sl2 < cnt) {
          int s = srcs[b0 + sl2];
          a = __expf(lrelu(as1[s * 8 + h] + adv) - m) * inv;
        }
        wlds[t * 64 + l] = a;
      }
      int sv = srcs[b0 + (l < cnt ? l : cnt - 1)];
      for (int j0 = 0; j0 < cnt; j0 += 8) {
        ushort2 uu[8];
        #pragma unroll
        for (int t2 = 0; t2 < 8; ++t2) {
          int slot = j0 + t2;
          int s = __builtin_amdgcn_readlane(sv, slot < cnt ? slot : 0);
          uu[t2] = *(const ushort2*)(base + (size_t)s * 128);
        }
        #pragma unroll
        for (int t2 = 0; t2 < 8; ++t2) {
          int slot = j0 + t2;
          float x0 = bf2f(uu[t2].x), x1 = bf2f(uu[t2].y);
          #pragma unroll
          for (int hh = 0; hh < 8; ++hh) {
            float w = wlds[slot * 8 + hh];
            acc[hh][0] += w * x0;
            acc[hh][1] += w * x1;
          }
        }
      }
    }
  }
  #pragma unroll
  for (int hh = 0; hh < 8; ++hh) {
    ushort2 o;
    o.x = f2bf(acc[hh][0]);
    o.y = f2bf(acc[hh][1]);
    *(ushort2*)(agg + (size_t)dst * 1024 + hh * 128 + l * 2) = o;
  }
}

// ---------------- fused softmax + SpMM layer2 (H=1), dst in [NCONS, NNODES) ----------------
__global__ __launch_bounds__(256) void fsp2(const int* __restrict__ offs,
                                            const int* __restrict__ csr_src,
                                            const float* __restrict__ a_src,
                                            const float* __restrict__ a_dst,
                                            const u16* __restrict__ xp2,
                                            const float* __restrict__ bias,
                                            u16* __restrict__ out) {
  int wvi = threadIdx.x >> 6;
  int dst = NCONS + blockIdx.x * 4 + wvi;
  if (dst >= NNODES) return;
  int l = threadIdx.x & 63;
  int off = offs[dst];
  int deg = offs[dst + 1] - off;
  const int* srcs = csr_src + off;
  float ad = a_dst[dst];
  const u16* base = xp2 + l * 2;
  float m = -1e30f, ssum = 0.f, a0 = 0.f, a1 = 0.f;
  for (int b0 = 0; b0 < deg; b0 += 64) {
    int cnt = deg - b0; if (cnt > 64) cnt = 64;
    int sv = srcs[b0 + (l < cnt ? l : cnt - 1)];
    float e = (l < cnt) ? lrelu(a_src[sv] + ad) : -1e30f;
    float mc = e;
    #pragma unroll
    for (int w = 1; w < 64; w <<= 1) mc = fmaxf(mc, __shfl_xor(mc, w, 64));
    float pex = __expf(e - mc);
    float sc = pex;
    #pragma unroll
    for (int w = 1; w < 64; w <<= 1) sc += __shfl_xor(sc, w, 64);
    float c0 = 0.f, c1 = 0.f;
    int j = 0;
    for (; j + 8 <= cnt; j += 8) {
      ushort2 uu[8];
      float ww[8];
      #pragma unroll
      for (int t = 0; t < 8; ++t) {
        int s = __builtin_amdgcn_readlane(sv, j + t);
        ww[t] = readlane_f(pex, j + t);
        uu[t] = *(const ushort2*)(base + (size_t)s * 128);
      }
      #pragma unroll
      for (int t = 0; t < 8; ++t) {
        c0 += ww[t] * bf2f(uu[t].x);
        c1 += ww[t] * bf2f(uu[t].y);
      }
    }
    for (; j < cnt; ++j) {
      int s = __builtin_amdgcn_readlane(sv, j);
      float w = readlane_f(pex, j);
      ushort2 u = *(const ushort2*)(base + (size_t)s * 128);
      c0 += w * bf2f(u.x);
      c1 += w * bf2f(u.y);
    }
    float nm = fmaxf(m, mc);
    float fo = __expf(m - nm), fn = __expf(mc - nm);
    a0 = a0 * fo + c0 * fn;
    a1 = a1 * fo + c1 * fn;
    ssum = ssum * fo + sc * fn;
    m = nm;
  }
  float inv = 1.f / (ssum + 1e-16f);
  int cg = l * 2;
  ushort2 o;
  o.x = f2bf(fmaxf(a0 * inv + bias[cg], 0.f));
  o.y = f2bf(fmaxf(a1 * inv + bias[cg + 1], 0.f));
  *(ushort2*)(out + (size_t)dst * 128 + cg) = o;
}

// ---------------- launch ----------------
extern "C" void kernel_launch(void* const* d_in, const int* in_sizes, int n_in,
                              void* d_out, int out_size, void* d_ws, size_t ws_size,
                              hipStream_t stream) {
  const float* cons    = (const float*)d_in[0];
  const float* cols    = (const float*)d_in[1];
  const float* node_W  = (const float*)d_in[2];
  const float* node_b  = (const float*)d_in[3];
  const float* col_W   = (const float*)d_in[4];
  const float* col_b   = (const float*)d_in[5];
  const float* W1      = (const float*)d_in[6];
  const float* att_s1  = (const float*)d_in[7];
  const float* att_d1  = (const float*)d_in[8];
  const float* b1      = (const float*)d_in[9];
  const float* W2      = (const float*)d_in[10];
  const float* att_s2  = (const float*)d_in[11];
  const float* att_d2  = (const float*)d_in[12];
  const float* b2      = (const float*)d_in[13];
  const float* out_W   = (const float*)d_in[14];
  const float* out_b   = (const float*)d_in[15];
  const int* edges     = (const int*)d_in[16];

  char* p = (char*)d_ws;
  auto alloc = [&](size_t bytes) {
    char* r = p;
    p += (bytes + 255) & ~(size_t)255;
    return r;
  };
  u16* emb0    = (u16*)alloc((size_t)NNODES * 128 * 2);        // bf16
  u16* agg     = (u16*)alloc((size_t)NNODES * 1024 * 2);       // bf16, node-major [N][8*128]
  u16* xp2     = (u16*)alloc((size_t)NNODES * 128 * 2);        // bf16
  u16* emb3    = (u16*)alloc((size_t)NNODES * 128 * 2);        // bf16
  u16* Wbf     = (u16*)alloc((size_t)(W1N + W2N + OWN) * 2);   // W1|W2|out_W contiguous
  u16* wsd     = (u16*)alloc((size_t)WSDN * 2);                // fused att vectors bf16
  // ---- contiguous zero region: as2, ad2, counts ----
  float* as2   = (float*)alloc((size_t)NNODES * 4);            // pads to 80128 B
  float* ad2   = (float*)alloc((size_t)NNODES * 4);            // pads to 80128 B
  int* counts  = (int*)alloc((size_t)NNODES * 4);              // pads to 80128 B
  size_t zspan = (char*)(counts + NNODES) - (char*)as2;
  // ---- end zero region ----
  float* as1   = (float*)alloc((size_t)NNODES * 8 * 4);
  float* ad1   = (float*)alloc((size_t)NNODES * 8 * 4);
  int* offs    = (int*)alloc((size_t)(NNODES + 1) * 4);
  int* cursor  = (int*)alloc((size_t)NNODES * 4);
  int* csrsrc  = (int*)alloc((size_t)NETOT * 4);
  int* lscan   = (int*)alloc((size_t)NSCANB * 256 * 4);
  int* bsum    = (int*)alloc((size_t)NSCANB * 4);

  u16* W1bf = Wbf;
  u16* W2bf = Wbf + W1N;
  u16* oWbf = Wbf + W1N + W2N;

  hipMemsetAsync(as2, 0, zspan, stream);

  // layer-0 embed + weight cvt + wsd + edge counting (fused)
  prep<<<(EMB0N + W1N + W2N + OWN + WSDN + 255) / 256, 256, 0, stream>>>(
      cons, cols, node_W, node_b, col_W, col_b, W1, W2, out_W, att_s1, att_d1,
      emb0, Wbf, wsd, edges, counts);

  // CSR build
  scan_a<<<NSCANB, 256, 0, stream>>>(counts, lscan, bsum);
  scan_c2<<<NSCANB, 256, 0, stream>>>(lscan, counts, bsum, offs, cursor);
  fill_edges<<<(NETOT + 255) / 256, 256, 0, stream>>>(edges, cursor, csrsrc);

  // GAT layer 1 (aggregate-then-transform): dots -> fused softmax+aggregate
  dots1_k<<<(NNODES + 63) / 64, 256, 0, stream>>>(emb0, wsd, as1, ad1);
  fagg1<<<(NNODES + 3) / 4, 256, 0, stream>>>(offs, csrsrc, as1, ad1, emb0, agg);

  // fused per-head transform: E_h in LDS chunk, xp2 accumulated across heads (+dots2)
  gemm12<<<NNODES / 32, 256, 0, stream>>>(agg, W1bf, b1, W2bf, att_s2, att_d2,
                                          as2, ad2, xp2);

  // GAT layer 2 aggregation: fused softmax+SpMM (dst >= NCONS only)
  fsp2<<<(NCOLSN + 3) / 4, 256, 0, stream>>>(offs, csrsrc, as2, ad2, xp2, b2, emb3);

  // output projection: rows 10000..19999, f32 out with bias
  gemm_bt<32><<<(NCOLSN + 31) / 32, 256, 0, stream>>>(
      emb3 + (size_t)NCONS * 128, oWbf, out_b, (float*)d_out, NCOLSN, 128, 128);
}

// Round 18
// 218.905 us; speedup vs baseline: 1.1541x; 1.0611x over previous
//
#include <hip/hip_runtime.h>

// ---------------- problem constants ----------------
#define NCONS 10000
#define NCOLSN 10000
#define NNODES 20000         // NCONS + NCOLSN
#define NEDGE 200000
#define NETOT 220000         // NEDGE + NNODES self loops
#define NEG_SLOPE 0.2f
#define NSCANB 79            // ceil(NNODES/256)

typedef unsigned short u16;
typedef __attribute__((ext_vector_type(8))) short bf16x8;
typedef __attribute__((ext_vector_type(4))) float f32x4;

__device__ __forceinline__ float bf2f(u16 u) {
  return __uint_as_float(((unsigned int)u) << 16);
}
__device__ __forceinline__ u16 f2bf(float f) {
  unsigned int x = __float_as_uint(f);
  return (u16)((x + 0x7fffu + ((x >> 16) & 1u)) >> 16);
}
__device__ __forceinline__ float lrelu(float v) {
  return v >= 0.f ? v : NEG_SLOPE * v;
}
// async global->LDS, 16 B per lane; LDS dest must be wave-uniform base + lane*16
__device__ __forceinline__ void gl2lds16(const u16* g, u16* l) {
  __builtin_amdgcn_global_load_lds(
      (const __attribute__((address_space(1))) unsigned int*)g,
      (__attribute__((address_space(3))) unsigned int*)l, 16, 0, 0);
}
__device__ __forceinline__ float readlane_f(float v, int j) {
  return __uint_as_float(__builtin_amdgcn_readlane(__float_as_uint(v), j));
}

#define W1N (1024 * 128)
#define W2N (128 * 1024)
#define OWN (128 * 128)
#define EMB0N (NNODES * 128)
#define WSDN (16 * 128)      // 16 fused attention vectors (8 ws + 8 wd), 128-dim

// ---------------- fused: layer-0 embed + weight cvt + wsd precompute + edge counting --------
__global__ void prep(const float* __restrict__ cons, const float* __restrict__ cols,
                     const float* __restrict__ nW, const float* __restrict__ nb,
                     const float* __restrict__ cW, const float* __restrict__ cb,
                     const float* __restrict__ W1, const float* __restrict__ W2,
                     const float* __restrict__ oW, const float* __restrict__ att_s1,
                     const float* __restrict__ att_d1, u16* __restrict__ emb,
                     u16* __restrict__ Wbf, u16* __restrict__ wsd,
                     const int* __restrict__ edges, int* __restrict__ counts) {
  int idx = blockIdx.x * 256 + threadIdx.x;
  if (idx < NETOT) {
    int dst = (idx < NEDGE) ? edges[NEDGE + idx] : (idx - NEDGE);
    atomicAdd(&counts[dst], 1);
  }
  if (idx < EMB0N) {
    int row = idx >> 7, o = idx & 127;
    float acc;
    if (row < NCONS) {
      acc = nb[o];
      #pragma unroll
      for (int k = 0; k < 4; ++k)
        acc += cons[row * 4 + k] * (nW[o * 8 + k] + nW[o * 8 + 4 + k]);
    } else {
      int r = row - NCONS;
      acc = cb[o];
      #pragma unroll
      for (int k = 0; k < 8; ++k)
        acc += cols[r * 8 + k] * (cW[o * 16 + k] + cW[o * 16 + 8 + k]);
    }
    emb[idx] = f2bf(fmaxf(acc, 0.f));
    return;
  }
  int i = idx - EMB0N;
  if (i < W1N + W2N + OWN) {
    float v;
    if (i < W1N) v = W1[i];
    else if (i < W1N + W2N) v = W2[i - W1N];
    else v = oW[i - W1N - W2N];
    Wbf[i] = f2bf(v);
    return;
  }
  int i2 = i - (W1N + W2N + OWN);
  if (i2 < WSDN) {
    int vec = i2 >> 7, k = i2 & 127;
    int h = vec & 7;
    const float* att = (vec < 8) ? att_s1 : att_d1;
    float a = 0.f;
    #pragma unroll 8
    for (int c = 0; c < 128; ++c)
      a += att[h * 128 + c] * W1[(size_t)(h * 128 + c) * 128 + k];
    wsd[i2] = f2bf(a);
  }
}

// ---------------- CSR build ----------------
__global__ void scan_a(const int* __restrict__ counts, int* __restrict__ lscan,
                       int* __restrict__ bsum) {
  __shared__ int sh[256];
  int t = threadIdx.x;
  int i = blockIdx.x * 256 + t;
  int v = (i < NNODES) ? counts[i] : 0;
  sh[t] = v;
  __syncthreads();
  for (int d = 1; d < 256; d <<= 1) {
    int add = (t >= d) ? sh[t - d] : 0;
    __syncthreads();
    sh[t] += add;
    __syncthreads();
  }
  lscan[i] = sh[t];
  if (t == 255) bsum[blockIdx.x] = sh[255];
}
__global__ void scan_c2(const int* __restrict__ lscan, const int* __restrict__ counts,
                        const int* __restrict__ bsum, int* __restrict__ offsets,
                        int* __restrict__ cursor) {
  __shared__ int sh[128];
  int t = threadIdx.x;
  if (t < 128) sh[t] = (t < NSCANB) ? bsum[t] : 0;
  __syncthreads();
  for (int d = 1; d < 128; d <<= 1) {
    int add = (t >= d && t < 128) ? sh[t - d] : 0;
    __syncthreads();
    if (t < 128) sh[t] += add;
    __syncthreads();
  }
  int bbase = (blockIdx.x > 0) ? sh[blockIdx.x - 1] : 0;
  int i = blockIdx.x * 256 + t;
  if (i == 0) offsets[0] = 0;
  if (i < NNODES) {
    int incl = lscan[i] + bbase;
    offsets[i + 1] = incl;
    cursor[i] = incl - counts[i];
  }
}

__global__ void fill_edges(const int* __restrict__ edges, int* __restrict__ cursor,
                           int* __restrict__ csr_src) {
  int i = blockIdx.x * 256 + threadIdx.x;
  if (i >= NETOT) return;
  int src, dst;
  if (i < NEDGE) { src = edges[i]; dst = edges[NEDGE + i]; }
  else { src = dst = i - NEDGE; }
  int pos = atomicAdd(&cursor[dst], 1);
  csr_src[pos] = src;
}

// ---------------- dots1: a_src/a_dst [N][8] = emb0 @ wsd^T via MFMA 16x16x32 ----------------
__global__ __launch_bounds__(256) void dots1_k(const u16* __restrict__ emb,
                                               const u16* __restrict__ wsd,
                                               float* __restrict__ as1,
                                               float* __restrict__ ad1) {
  int wv = threadIdx.x >> 6, lane = threadIdx.x & 63;
  int quad = lane >> 4, l16 = lane & 15;
  int m0 = blockIdx.x * 64 + wv * 16;
  int ra = m0 + l16; if (ra >= NNODES) ra = NNODES - 1;
  f32x4 acc = f32x4{0.f, 0.f, 0.f, 0.f};
  #pragma unroll
  for (int k0 = 0; k0 < 128; k0 += 32) {
    bf16x8 a = *(const bf16x8*)(emb + (size_t)ra * 128 + k0 + quad * 8);
    bf16x8 b = *(const bf16x8*)(wsd + (size_t)l16 * 128 + k0 + quad * 8);
    acc = __builtin_amdgcn_mfma_f32_16x16x32_bf16(a, b, acc, 0, 0, 0);
  }
  #pragma unroll
  for (int r = 0; r < 4; ++r) {
    int node = m0 + quad * 4 + r;
    if (node < NNODES) {
      if (l16 < 8) as1[node * 8 + l16] = acc[r];
      else         ad1[node * 8 + (l16 - 8)] = acc[r];
    }
  }
}

// ---------------- fused per-head transform GEMM, barrier-amortized ----------------
// 625 blocks x 32 rows. Per head: stage full agg slice (4x[32x32] chunks, 8 KB) + full
// W1 head-slice (4x[128x32], 32 KB) -> 1 barrier -> 16 MFMAs -> sE (stride 136, VALU
// scatter OK) -> 1 barrier -> stage full W2 col-slice (32 KB, reuse sB) -> 1 barrier ->
// 16 MFMAs -> 1 barrier. 4 barriers/head vs 17. LDS 48.7 KB -> 3 blocks/CU.
__global__ __launch_bounds__(256) void gemm12(const u16* __restrict__ agg,
                                              const u16* __restrict__ W1bf,
                                              const float* __restrict__ b1,
                                              const u16* __restrict__ W2bf,
                                              const float* __restrict__ att_s,
                                              const float* __restrict__ att_d,
                                              float* __restrict__ as2,
                                              float* __restrict__ ad2,
                                              u16* __restrict__ xp2) {
  __shared__ u16 sA[4 * 32 * 32];      // 8 KB: 4 chunks of [32 rows x 32 k]
  __shared__ u16 sB[4 * 128 * 32];     // 32 KB: 4 chunks of [128 rows x 32 k]
  __shared__ u16 sE[32 * 136];         // 8.7 KB, padded stride
  int tid = threadIdx.x;
  int wv = tid >> 6, lane = tid & 63, quad = lane >> 4, l16 = lane & 15;
  int m0 = blockIdx.x * 32;            // 625*32 == 20000 exactly
  int rm = (wv >> 1) * 16, cn = (wv & 1) * 64;

  f32x4 acc2[4];
  #pragma unroll
  for (int ni = 0; ni < 4; ++ni) acc2[ni] = f32x4{0.f, 0.f, 0.f, 0.f};

  for (int h = 0; h < 8; ++h) {
    // ---- stage agg slice (2 passes) + W1 head slice (8 passes) ----
    #pragma unroll
    for (int pas = 0; pas < 2; ++pas) {
      int off = pas * 4096 + tid * 16;               // byte offset in sA
      int c = off >> 11, r = (off & 2047) >> 6, kk = (off & 63) >> 1;
      gl2lds16(agg + (size_t)(m0 + r) * 1024 + h * 128 + c * 32 + kk, &sA[off >> 1]);
    }
    #pragma unroll
    for (int pas = 0; pas < 8; ++pas) {
      int off = pas * 4096 + tid * 16;               // byte offset in sB
      int c = off >> 13, r = (off & 8191) >> 6, kk = (off & 63) >> 1;
      gl2lds16(W1bf + (size_t)(h * 128 + r) * 128 + c * 32 + kk, &sB[off >> 1]);
    }
    __syncthreads();
    // ---- phase A: E_h = relu(agg_h @ W1_h^T + b1_h), 16 MFMAs ----
    f32x4 acc1[4];
    #pragma unroll
    for (int ni = 0; ni < 4; ++ni) acc1[ni] = f32x4{0.f, 0.f, 0.f, 0.f};
    #pragma unroll
    for (int c = 0; c < 4; ++c) {
      bf16x8 af = *(const bf16x8*)&sA[c * 1024 + (rm + l16) * 32 + quad * 8];
      #pragma unroll
      for (int ni = 0; ni < 4; ++ni) {
        bf16x8 bfv = *(const bf16x8*)&sB[c * 4096 + (cn + ni * 16 + l16) * 32 + quad * 8];
        acc1[ni] = __builtin_amdgcn_mfma_f32_16x16x32_bf16(af, bfv, acc1[ni], 0, 0, 0);
      }
    }
    #pragma unroll
    for (int ni = 0; ni < 4; ++ni) {
      int col = cn + ni * 16 + l16;
      float bv = b1[h * 128 + col];
      #pragma unroll
      for (int r = 0; r < 4; ++r)
        sE[(rm + quad * 4 + r) * 136 + col] = f2bf(fmaxf(acc1[ni][r] + bv, 0.f));
    }
    __syncthreads();
    // ---- stage W2 column-slice (reuse sB) ----
    #pragma unroll
    for (int pas = 0; pas < 8; ++pas) {
      int off = pas * 4096 + tid * 16;
      int c = off >> 13, r = (off & 8191) >> 6, kk = (off & 63) >> 1;
      gl2lds16(W2bf + (size_t)r * 1024 + h * 128 + c * 32 + kk, &sB[off >> 1]);
    }
    __syncthreads();
    // ---- phase B: xp2 += E_h @ W2_h^T, 16 MFMAs ----
    #pragma unroll
    for (int c = 0; c < 4; ++c) {
      bf16x8 af = *(const bf16x8*)&sE[(rm + l16) * 136 + c * 32 + quad * 8];
      #pragma unroll
      for (int ni = 0; ni < 4; ++ni) {
        bf16x8 bfv = *(const bf16x8*)&sB[c * 4096 + (cn + ni * 16 + l16) * 32 + quad * 8];
        acc2[ni] = __builtin_amdgcn_mfma_f32_16x16x32_bf16(af, bfv, acc2[ni], 0, 0, 0);
      }
    }
    __syncthreads();
  }

  // DOTS epilogue (H=1) + xp2 write
  float av_s[4], av_d[4];
  #pragma unroll
  for (int ni = 0; ni < 4; ++ni) {
    int col = cn + ni * 16 + l16;
    av_s[ni] = att_s[col];
    av_d[ni] = att_d[col];
  }
  #pragma unroll
  for (int r = 0; r < 4; ++r) {
    float sp = 0.f, dp = 0.f;
    #pragma unroll
    for (int ni = 0; ni < 4; ++ni) {
      sp += acc2[ni][r] * av_s[ni];
      dp += acc2[ni][r] * av_d[ni];
    }
    #pragma unroll
    for (int w = 1; w < 16; w <<= 1) {
      sp += __shfl_xor(sp, w, 64);
      dp += __shfl_xor(dp, w, 64);
    }
    int orow = m0 + rm + quad * 4 + r;
    if (l16 == 0) {
      atomicAdd(&as2[orow], sp);
      atomicAdd(&ad2[orow], dp);
    }
  }
  #pragma unroll
  for (int ni = 0; ni < 4; ++ni) {
    int col = cn + ni * 16 + l16;
    #pragma unroll
    for (int r = 0; r < 4; ++r) {
      int orow = m0 + rm + quad * 4 + r;
      xp2[(size_t)orow * 128 + col] = f2bf(acc2[ni][r]);
    }
  }
}

// ---------------- LDS-staged GEMM (gemm3 only): C[M,N] = A[M,K] @ B[N,K]^T ----------------
template <int BM>
__global__ __launch_bounds__(256) void gemm_bt(const u16* __restrict__ A, const u16* __restrict__ B,
                                               const float* __restrict__ bias, float* __restrict__ C,
                                               int M, int N, int K) {
  constexpr int MI = BM / 32;
  __shared__ u16 sA[BM * 32];
  __shared__ u16 sB[128 * 32];
  int tid = threadIdx.x;
  int wv = tid >> 6;
  int lane = tid & 63;
  int quad = lane >> 4;
  int l16 = lane & 15;
  int m0 = blockIdx.x * BM;
  int rm = (wv >> 1) * (16 * MI);
  int cn = (wv & 1) * 64;

  f32x4 acc[MI][4];
  #pragma unroll
  for (int mi = 0; mi < MI; ++mi)
    #pragma unroll
    for (int ni = 0; ni < 4; ++ni) acc[mi][ni] = f32x4{0.f, 0.f, 0.f, 0.f};

  for (int k0 = 0; k0 < K; k0 += 32) {
    for (int off = tid * 16; off < BM * 64; off += 4096) {
      int row = off >> 6;
      int kk = (off & 63) >> 1;
      int rg = m0 + row; if (rg >= M) rg = M - 1;
      gl2lds16(A + (size_t)rg * K + k0 + kk, &sA[off >> 1]);
    }
    for (int off = tid * 16; off < 128 * 64; off += 4096) {
      int row = off >> 6;
      int kk = (off & 63) >> 1;
      gl2lds16(B + (size_t)row * K + k0 + kk, &sB[off >> 1]);
    }
    __syncthreads();
    bf16x8 af[MI], bfv[4];
    #pragma unroll
    for (int mi = 0; mi < MI; ++mi)
      af[mi] = *(const bf16x8*)&sA[(rm + mi * 16 + l16) * 32 + quad * 8];
    #pragma unroll
    for (int ni = 0; ni < 4; ++ni)
      bfv[ni] = *(const bf16x8*)&sB[(cn + ni * 16 + l16) * 32 + quad * 8];
    #pragma unroll
    for (int mi = 0; mi < MI; ++mi)
      #pragma unroll
      for (int ni = 0; ni < 4; ++ni)
        acc[mi][ni] = __builtin_amdgcn_mfma_f32_16x16x32_bf16(af[mi], bfv[ni], acc[mi][ni], 0, 0, 0);
    __syncthreads();
  }

  #pragma unroll
  for (int ni = 0; ni < 4; ++ni) {
    int col = cn + ni * 16 + l16;
    float bv = bias[col];
    #pragma unroll
    for (int mi = 0; mi < MI; ++mi) {
      #pragma unroll
      for (int r = 0; r < 4; ++r) {
        int orow = m0 + rm + mi * 16 + quad * 4 + r;
        if (orow < M) C[(size_t)orow * N + col] = acc[mi][ni][r] + bv;
      }
    }
  }
}

// ---------------- fagg1: fused softmax + multi-head aggregate, agg = A_alpha @ emb0 --------
__global__ __launch_bounds__(256) void fagg1(const int* __restrict__ offs,
                                             const int* __restrict__ csr_src,
                                             const float* __restrict__ as1,
                                             const float* __restrict__ ad1,
                                             const u16* __restrict__ emb,
                                             u16* __restrict__ agg) {
  __shared__ float alds[4 * 512];
  int wvi = threadIdx.x >> 6;
  int dst = blockIdx.x * 4 + wvi;
  if (dst >= NNODES) return;
  int l = threadIdx.x & 63;
  int h = l & 7, i = l >> 3;
  float* wlds = &alds[wvi * 512];
  int off = offs[dst];
  int deg = offs[dst + 1] - off;
  const int* srcs = csr_src + off;
  float adv = ad1[dst * 8 + h];
  const u16* base = emb + l * 2;
  float acc[8][2];
  #pragma unroll
  for (int hh = 0; hh < 8; ++hh) { acc[hh][0] = 0.f; acc[hh][1] = 0.f; }

  if (deg <= 64) {
    int sl = srcs[l < deg ? l : deg - 1];
    float g[8];
    #pragma unroll
    for (int t = 0; t < 8; ++t) {
      int jj = t * 8 + i;
      int s = __builtin_amdgcn_readlane(sl, jj < deg ? jj : 0);
      g[t] = as1[s * 8 + h];
    }
    float m = -1e30f, ssum = 0.f, ev[8];
    #pragma unroll
    for (int t = 0; t < 8; ++t) {
      int jj = t * 8 + i;
      float e = (jj < deg) ? lrelu(g[t] + adv) : -1e30f;
      ev[t] = e;
      float nm = fmaxf(m, e);
      ssum = ssum * __expf(m - nm) + ((jj < deg) ? __expf(e - nm) : 0.f);
      m = nm;
    }
    #pragma unroll
    for (int w = 8; w < 64; w <<= 1) {
      float om = __shfl_xor(m, w, 64);
      float os = __shfl_xor(ssum, w, 64);
      float nm = fmaxf(m, om);
      ssum = ssum * __expf(m - nm) + os * __expf(om - nm);
      m = nm;
    }
    float inv = 1.f / (ssum + 1e-16f);
    #pragma unroll
    for (int t = 0; t < 8; ++t)
      wlds[t * 64 + l] = __expf(ev[t] - m) * inv;
    for (int j0 = 0; j0 < deg; j0 += 8) {
      ushort2 uu[8];
      #pragma unroll
      for (int t2 = 0; t2 < 8; ++t2) {
        int slot = j0 + t2;
        int s = __builtin_amdgcn_readlane(sl, slot < deg ? slot : 0);
        uu[t2] = *(const ushort2*)(base + (size_t)s * 128);
      }
      #pragma unroll
      for (int t2 = 0; t2 < 8; ++t2) {
        int slot = j0 + t2;
        float x0 = bf2f(uu[t2].x), x1 = bf2f(uu[t2].y);
        #pragma unroll
        for (int hh = 0; hh < 8; ++hh) {
          float w = wlds[slot * 8 + hh];
          acc[hh][0] += w * x0;
          acc[hh][1] += w * x1;
        }
      }
    }
  } else {
    float m = -1e30f, ssum = 0.f;
    for (int j = i; j < deg; j += 8) {
      int s = srcs[j];
      float e = lrelu(as1[s * 8 + h] + adv);
      float nm = fmaxf(m, e);
      ssum = ssum * __expf(m - nm) + __expf(e - nm);
      m = nm;
    }
    #pragma unroll
    for (int w = 8; w < 64; w <<= 1) {
      float om = __shfl_xor(m, w, 64);
      float os = __shfl_xor(ssum, w, 64);
      float nm = fmaxf(m, om);
      ssum = ssum * __expf(m - nm) + os * __expf(om - nm);
      m = nm;
    }
    float inv = 1.f / (ssum + 1e-16f);
    for (int b0 = 0; b0 < deg; b0 += 64) {
      int cnt = deg - b0; if (cnt > 64) cnt = 64;
      #pragma unroll
      for (int t = 0; t < 8; ++t) {
        int sl2 = t * 8 + i;
        float a = 0.f;
        if (sl2 < cnt) {
          int s = srcs[b0 + sl2];
          a = __expf(lrelu(as1[s * 8 + h] + adv) - m) * inv;
        }
        wlds[t * 64 + l] = a;
      }
      int sv = srcs[b0 + (l < cnt ? l : cnt - 1)];
      for (int j0 = 0; j0 < cnt; j0 += 8) {
        ushort2 uu[8];
        #pragma unroll
        for (int t2 = 0; t2 < 8; ++t2) {
          int slot = j0 + t2;
          int s = __builtin_amdgcn_readlane(sv, slot < cnt ? slot : 0);
          uu[t2] = *(const ushort2*)(base + (size_t)s * 128);
        }
        #pragma unroll
        for (int t2 = 0; t2 < 8; ++t2) {
          int slot = j0 + t2;
          float x0 = bf2f(uu[t2].x), x1 = bf2f(uu[t2].y);
          #pragma unroll
          for (int hh = 0; hh < 8; ++hh) {
            float w = wlds[slot * 8 + hh];
            acc[hh][0] += w * x0;
            acc[hh][1] += w * x1;
          }
        }
      }
    }
  }
  #pragma unroll
  for (int hh = 0; hh < 8; ++hh) {
    ushort2 o;
    o.x = f2bf(acc[hh][0]);
    o.y = f2bf(acc[hh][1]);
    *(ushort2*)(agg + (size_t)dst * 1024 + hh * 128 + l * 2) = o;
  }
}

// ---------------- fused softmax + SpMM layer2 (H=1), dst in [NCONS, NNODES) ----------------
__global__ __launch_bounds__(256) void fsp2(const int* __restrict__ offs,
                                            const int* __restrict__ csr_src,
                                            const float* __restrict__ a_src,
                                            const float* __restrict__ a_dst,
                                            const u16* __restrict__ xp2,
                                            const float* __restrict__ bias,
                                            u16* __restrict__ out) {
  int wvi = threadIdx.x >> 6;
  int dst = NCONS + blockIdx.x * 4 + wvi;
  if (dst >= NNODES) return;
  int l = threadIdx.x & 63;
  int off = offs[dst];
  int deg = offs[dst + 1] - off;
  const int* srcs = csr_src + off;
  float ad = a_dst[dst];
  const u16* base = xp2 + l * 2;
  float m = -1e30f, ssum = 0.f, a0 = 0.f, a1 = 0.f;
  for (int b0 = 0; b0 < deg; b0 += 64) {
    int cnt = deg - b0; if (cnt > 64) cnt = 64;
    int sv = srcs[b0 + (l < cnt ? l : cnt - 1)];
    float e = (l < cnt) ? lrelu(a_src[sv] + ad) : -1e30f;
    float mc = e;
    #pragma unroll
    for (int w = 1; w < 64; w <<= 1) mc = fmaxf(mc, __shfl_xor(mc, w, 64));
    float pex = __expf(e - mc);
    float sc = pex;
    #pragma unroll
    for (int w = 1; w < 64; w <<= 1) sc += __shfl_xor(sc, w, 64);
    float c0 = 0.f, c1 = 0.f;
    int j = 0;
    for (; j + 8 <= cnt; j += 8) {
      ushort2 uu[8];
      float ww[8];
      #pragma unroll
      for (int t = 0; t < 8; ++t) {
        int s = __builtin_amdgcn_readlane(sv, j + t);
        ww[t] = readlane_f(pex, j + t);
        uu[t] = *(const ushort2*)(base + (size_t)s * 128);
      }
      #pragma unroll
      for (int t = 0; t < 8; ++t) {
        c0 += ww[t] * bf2f(uu[t].x);
        c1 += ww[t] * bf2f(uu[t].y);
      }
    }
    for (; j < cnt; ++j) {
      int s = __builtin_amdgcn_readlane(sv, j);
      float w = readlane_f(pex, j);
      ushort2 u = *(const ushort2*)(base + (size_t)s * 128);
      c0 += w * bf2f(u.x);
      c1 += w * bf2f(u.y);
    }
    float nm = fmaxf(m, mc);
    float fo = __expf(m - nm), fn = __expf(mc - nm);
    a0 = a0 * fo + c0 * fn;
    a1 = a1 * fo + c1 * fn;
    ssum = ssum * fo + sc * fn;
    m = nm;
  }
  float inv = 1.f / (ssum + 1e-16f);
  int cg = l * 2;
  ushort2 o;
  o.x = f2bf(fmaxf(a0 * inv + bias[cg], 0.f));
  o.y = f2bf(fmaxf(a1 * inv + bias[cg + 1], 0.f));
  *(ushort2*)(out + (size_t)dst * 128 + cg) = o;
}

// ---------------- launch ----------------
extern "C" void kernel_launch(void* const* d_in, const int* in_sizes, int n_in,
                              void* d_out, int out_size, void* d_ws, size_t ws_size,
                              hipStream_t stream) {
  const float* cons    = (const float*)d_in[0];
  const float* cols    = (const float*)d_in[1];
  const float* node_W  = (const float*)d_in[2];
  const float* node_b  = (const float*)d_in[3];
  const float* col_W   = (const float*)d_in[4];
  const float* col_b   = (const float*)d_in[5];
  const float* W1      = (const float*)d_in[6];
  const float* att_s1  = (const float*)d_in[7];
  const float* att_d1  = (const float*)d_in[8];
  const float* b1      = (const float*)d_in[9];
  const float* W2      = (const float*)d_in[10];
  const float* att_s2  = (const float*)d_in[11];
  const float* att_d2  = (const float*)d_in[12];
  const float* b2      = (const float*)d_in[13];
  const float* out_W   = (const float*)d_in[14];
  const float* out_b   = (const float*)d_in[15];
  const int* edges     = (const int*)d_in[16];

  char* p = (char*)d_ws;
  auto alloc = [&](size_t bytes) {
    char* r = p;
    p += (bytes + 255) & ~(size_t)255;
    return r;
  };
  u16* emb0    = (u16*)alloc((size_t)NNODES * 128 * 2);        // bf16
  u16* agg     = (u16*)alloc((size_t)NNODES * 1024 * 2);       // bf16, node-major [N][8*128]
  u16* xp2     = (u16*)alloc((size_t)NNODES * 128 * 2);        // bf16
  u16* emb3    = (u16*)alloc((size_t)NNODES * 128 * 2);        // bf16
  u16* Wbf     = (u16*)alloc((size_t)(W1N + W2N + OWN) * 2);   // W1|W2|out_W contiguous
  u16* wsd     = (u16*)alloc((size_t)WSDN * 2);                // fused att vectors bf16
  // ---- contiguous zero region: as2, ad2, counts ----
  float* as2   = (float*)alloc((size_t)NNODES * 4);            // pads to 80128 B
  float* ad2   = (float*)alloc((size_t)NNODES * 4);            // pads to 80128 B
  int* counts  = (int*)alloc((size_t)NNODES * 4);              // pads to 80128 B
  size_t zspan = (char*)(counts + NNODES) - (char*)as2;
  // ---- end zero region ----
  float* as1   = (float*)alloc((size_t)NNODES * 8 * 4);
  float* ad1   = (float*)alloc((size_t)NNODES * 8 * 4);
  int* offs    = (int*)alloc((size_t)(NNODES + 1) * 4);
  int* cursor  = (int*)alloc((size_t)NNODES * 4);
  int* csrsrc  = (int*)alloc((size_t)NETOT * 4);
  int* lscan   = (int*)alloc((size_t)NSCANB * 256 * 4);
  int* bsum    = (int*)alloc((size_t)NSCANB * 4);

  u16* W1bf = Wbf;
  u16* W2bf = Wbf + W1N;
  u16* oWbf = Wbf + W1N + W2N;

  hipMemsetAsync(as2, 0, zspan, stream);

  // layer-0 embed + weight cvt + wsd + edge counting (fused)
  prep<<<(EMB0N + W1N + W2N + OWN + WSDN + 255) / 256, 256, 0, stream>>>(
      cons, cols, node_W, node_b, col_W, col_b, W1, W2, out_W, att_s1, att_d1,
      emb0, Wbf, wsd, edges, counts);

  // CSR build
  scan_a<<<NSCANB, 256, 0, stream>>>(counts, lscan, bsum);
  scan_c2<<<NSCANB, 256, 0, stream>>>(lscan, counts, bsum, offs, cursor);
  fill_edges<<<(NETOT + 255) / 256, 256, 0, stream>>>(edges, cursor, csrsrc);

  // GAT layer 1 (aggregate-then-transform): dots -> fused softmax+aggregate
  dots1_k<<<(NNODES + 63) / 64, 256, 0, stream>>>(emb0, wsd, as1, ad1);
  fagg1<<<(NNODES + 3) / 4, 256, 0, stream>>>(offs, csrsrc, as1, ad1, emb0, agg);

  // fused per-head transform, barrier-amortized (+dots2)
  gemm12<<<NNODES / 32, 256, 0, stream>>>(agg, W1bf, b1, W2bf, att_s2, att_d2,
                                          as2, ad2, xp2);

  // GAT layer 2 aggregation: fused softmax+SpMM (dst >= NCONS only)
  fsp2<<<(NCOLSN + 3) / 4, 256, 0, stream>>>(offs, csrsrc, as2, ad2, xp2, b2, emb3);

  // output projection: rows 10000..19999, f32 out with bias
  gemm_bt<32><<<(NCOLSN + 31) / 32, 256, 0, stream>>>(
      emb3 + (size_t)NCONS * 128, oWbf, out_b, (float*)d_out, NCOLSN, 128, 128);
}